// Round 1
// baseline (808.561 us; speedup 1.0000x reference)
//
#include <hip/hip_runtime.h>
#include <hip/hip_bf16.h>

typedef float f32x4 __attribute__((ext_vector_type(4)));
typedef __bf16 bf16x8 __attribute__((ext_vector_type(8)));

#define D_MODEL 1024
#define D_INNER 2048
#define NROWS   2048   // B*T
#define TLEN    1024
#define N2      2176   // d_inner + 2*d_state (dt_w | Bp | Cp fused)

// round-to-nearest-even f32 -> bf16 bits (finite inputs)
__device__ __forceinline__ unsigned short f2bf(float f) {
    unsigned int u = __float_as_uint(f);
    u += 0x7fffu + ((u >> 16) & 1u);
    return (unsigned short)(u >> 16);
}

// ---------------- LayerNorm -> bf16 h ----------------
__global__ __launch_bounds__(256) void ln_k(
    const float* __restrict__ x, const float* __restrict__ wgt,
    const float* __restrict__ bia, unsigned short* __restrict__ h)
{
    const int r = blockIdx.x;
    const int tid = threadIdx.x;
    const float4 v = *(const float4*)(x + (size_t)r * D_MODEL + tid * 4);
    float s1 = v.x + v.y + v.z + v.w;
    float s2 = v.x * v.x + v.y * v.y + v.z * v.z + v.w * v.w;
#pragma unroll
    for (int off = 1; off < 64; off <<= 1) {
        s1 += __shfl_xor(s1, off);
        s2 += __shfl_xor(s2, off);
    }
    __shared__ float red[8];
    const int lane = tid & 63, wv = tid >> 6;
    if (lane == 0) { red[wv * 2] = s1; red[wv * 2 + 1] = s2; }
    __syncthreads();
    s1 = red[0] + red[2] + red[4] + red[6];
    s2 = red[1] + red[3] + red[5] + red[7];
    const float mu  = s1 * (1.f / D_MODEL);
    const float var = s2 * (1.f / D_MODEL) - mu * mu;
    const float rs  = rsqrtf(var + 1e-5f);
    const float4 w4 = *(const float4*)(wgt + tid * 4);
    const float4 b4 = *(const float4*)(bia + tid * 4);
    ushort4 o;
    o.x = f2bf((v.x - mu) * rs * w4.x + b4.x);
    o.y = f2bf((v.y - mu) * rs * w4.y + b4.y);
    o.z = f2bf((v.z - mu) * rs * w4.z + b4.z);
    o.w = f2bf((v.w - mu) * rs * w4.w + b4.w);
    *(ushort4*)(h + (size_t)r * D_MODEL + tid * 4) = o;
}

// ---------------- transpose + cast f32[K][N] -> bf16 dst[n][k] (row stride LD) ----------------
__global__ __launch_bounds__(256) void tcast(
    const float* __restrict__ src, unsigned short* __restrict__ dst,
    int K, int N, int LD)
{
    __shared__ float tile[32][33];
    const int n0 = blockIdx.x * 32;
    const int k0 = blockIdx.y * 32;
    const int tx = threadIdx.x & 31;
    const int ty = (threadIdx.x >> 5) * 4;
#pragma unroll
    for (int i = 0; i < 4; ++i)
        tile[ty + i][tx] = src[(size_t)(k0 + ty + i) * N + n0 + tx];
    __syncthreads();
#pragma unroll
    for (int i = 0; i < 4; ++i)
        dst[(size_t)(n0 + ty + i) * LD + k0 + tx] = f2bf(tile[tx][ty + i]);
}

// ---------------- bf16 MFMA GEMM: C[M,N] f32 = A[M,K] * BT[N,K]^T (+ add_src) ----------------
// 128x128 tile, BK=32, 4 waves (2x2), each wave 64x64 = 4x4 fragments of 16x16x32.
// C/D layout (m89-verified): col = lane&15, row = (lane>>4)*4 + i.
__global__ __launch_bounds__(256) void gemm_bt(
    const unsigned short* __restrict__ A,
    const unsigned short* __restrict__ BT,
    float* __restrict__ C,
    const float* __restrict__ add_src,
    int M, int N, int K)
{
    constexpr int LDK = 40; // 32 + 8 pad: conflict-free b128 fragment reads
    __shared__ unsigned short As[128 * LDK];
    __shared__ unsigned short Bs[128 * LDK];

    const int tid  = threadIdx.x;
    const int lane = tid & 63;
    const int wave = tid >> 6;
    const int wr = wave >> 1;
    const int wc = wave & 1;
    const int row0 = blockIdx.y * 128;
    const int col0 = blockIdx.x * 128;

    f32x4 acc[4][4] = {};

    const int g_row = tid >> 2;        // 0..63
    const int g_col = (tid & 3) * 8;   // 0,8,16,24
    const unsigned short* Ap = A  + (size_t)(row0 + g_row) * K + g_col;
    const unsigned short* Bq = BT + (size_t)(col0 + g_row) * K + g_col;
    const size_t rstep = (size_t)64 * K;

    const int nk = K >> 5;
    uint4 ra0 = *(const uint4*)Ap;
    uint4 ra1 = *(const uint4*)(Ap + rstep);
    uint4 rb0 = *(const uint4*)Bq;
    uint4 rb1 = *(const uint4*)(Bq + rstep);

    const int wrow = g_row * LDK + g_col;
    const int qa = (lane >> 4) * 8;
    const int fr = lane & 15;

    for (int kt = 0; kt < nk; ++kt) {
        *(uint4*)&As[wrow]            = ra0;
        *(uint4*)&As[wrow + 64 * LDK] = ra1;
        *(uint4*)&Bs[wrow]            = rb0;
        *(uint4*)&Bs[wrow + 64 * LDK] = rb1;
        __syncthreads();
        if (kt + 1 < nk) {
            const unsigned short* An = Ap + (size_t)(kt + 1) * 32;
            const unsigned short* Bn = Bq + (size_t)(kt + 1) * 32;
            ra0 = *(const uint4*)An;
            ra1 = *(const uint4*)(An + rstep);
            rb0 = *(const uint4*)Bn;
            rb1 = *(const uint4*)(Bn + rstep);
        }
        bf16x8 af[4], bfr[4];
#pragma unroll
        for (int m = 0; m < 4; ++m)
            af[m] = *(const bf16x8*)&As[(wr * 64 + m * 16 + fr) * LDK + qa];
#pragma unroll
        for (int n = 0; n < 4; ++n)
            bfr[n] = *(const bf16x8*)&Bs[(wc * 64 + n * 16 + fr) * LDK + qa];
#pragma unroll
        for (int m = 0; m < 4; ++m)
#pragma unroll
            for (int n = 0; n < 4; ++n)
                acc[m][n] = __builtin_amdgcn_mfma_f32_16x16x32_bf16(af[m], bfr[n], acc[m][n], 0, 0, 0);
        __syncthreads();
    }

    const int crow = row0 + wr * 64;
    const int ccol = col0 + wc * 64 + fr;
    const int rsub = (lane >> 4) * 4;
#pragma unroll
    for (int m = 0; m < 4; ++m) {
#pragma unroll
        for (int n = 0; n < 4; ++n) {
#pragma unroll
            for (int i = 0; i < 4; ++i) {
                const size_t off = (size_t)(crow + m * 16 + rsub + i) * N + (ccol + n * 16);
                float v = acc[m][n][i];
                if (add_src) v += add_src[off];
                C[off] = v;
            }
        }
    }
}

// ---------------- causal depthwise conv(4) + bias + SiLU ----------------
__global__ __launch_bounds__(256) void conv_silu(
    const float* __restrict__ xz, const float* __restrict__ cw,
    const float* __restrict__ cb, float* __restrict__ xs,
    unsigned short* __restrict__ xsb)
{
    const int idx = blockIdx.x * 256 + threadIdx.x;
    const int c = idx & (D_INNER - 1);
    const int r = idx >> 11;
    const int t = r & (TLEN - 1);
    const float* base = xz + (size_t)r * 4096 + c;
    float acc = base[0] * cw[c * 4 + 3];
    if (t >= 1) acc += base[-4096]  * cw[c * 4 + 2];
    if (t >= 2) acc += base[-8192]  * cw[c * 4 + 1];
    if (t >= 3) acc += base[-12288] * cw[c * 4 + 0];
    acc += cb[c];
    const float s = acc / (1.f + __expf(-acc));
    xs[idx]  = s;
    xsb[idx] = f2bf(s);
}

// ---------------- softplus(dt_pre + dt_b) ----------------
__global__ __launch_bounds__(256) void softplus_k(
    const float* __restrict__ xw2, const float* __restrict__ dtb,
    float* __restrict__ dt)
{
    const int idx = blockIdx.x * 256 + threadIdx.x;
    const int c = idx & (D_INNER - 1);
    const int r = idx >> 11;
    const float v = xw2[(size_t)r * N2 + c] + dtb[c];
    dt[idx] = (v > 15.f) ? v : log1pf(__expf(v));
}

// ---------------- sequential selective scan: one wave per (b,d), lane = state ----------------
__global__ __launch_bounds__(256) void scan_k(
    const float* __restrict__ dt, const float* __restrict__ xs,
    const float* __restrict__ xw2, const float* __restrict__ A_log,
    float* __restrict__ y)
{
    const int lane = threadIdx.x & 63;
    const int wave = threadIdx.x >> 6;
    const int gd = blockIdx.x * 4 + wave;   // 0..4095 over (b,d)
    const int b = gd >> 11;
    const int d = gd & (D_INNER - 1);

    const float Aa = -__expf(A_log[d * 64 + lane]);
    const float* bc  = xw2 + (size_t)b * TLEN * N2 + D_INNER; // B at +0, C at +64
    const float* dtp = dt + (size_t)b * TLEN * D_INNER + d;
    const float* xp  = xs + (size_t)b * TLEN * D_INNER + d;
    float*       yp  = y  + (size_t)b * TLEN * D_INNER + d;

    float st = 0.f;
    for (int t = 0; t < TLEN; ++t) {
        const float Bv  = bc[(size_t)t * N2 + lane];
        const float Cv  = bc[(size_t)t * N2 + 64 + lane];
        const float dtv = dtp[(size_t)t * D_INNER];
        const float xv  = xp[(size_t)t * D_INNER];
        const float dA  = __expf(dtv * Aa);
        st = st * dA + (dtv * xv) * Bv;
        float p = st * Cv;
        p += __shfl_xor(p, 1);
        p += __shfl_xor(p, 2);
        p += __shfl_xor(p, 4);
        p += __shfl_xor(p, 8);
        p += __shfl_xor(p, 16);
        p += __shfl_xor(p, 32);
        if (lane == 0) yp[(size_t)t * D_INNER] = p;
    }
}

// ---------------- y' = (y + xs*D) * silu(z) -> bf16 ----------------
__global__ __launch_bounds__(256) void combine_k(
    const float* __restrict__ y, const float* __restrict__ xs,
    const float* __restrict__ Dv, const float* __restrict__ xz,
    unsigned short* __restrict__ y2b)
{
    const int idx = blockIdx.x * 256 + threadIdx.x;
    const int c = idx & (D_INNER - 1);
    const int r = idx >> 11;
    const float z  = xz[(size_t)r * 4096 + D_INNER + c];
    const float sz = z / (1.f + __expf(-z));
    const float v  = (y[idx] + xs[idx] * Dv[c]) * sz;
    y2b[idx] = f2bf(v);
}

extern "C" void kernel_launch(void* const* d_in, const int* in_sizes, int n_in,
                              void* d_out, int out_size, void* d_ws, size_t ws_size,
                              hipStream_t stream)
{
    const float* x      = (const float*)d_in[0];
    const float* norm_w = (const float*)d_in[1];
    const float* norm_b = (const float*)d_in[2];
    const float* Win    = (const float*)d_in[3];
    const float* conv_w = (const float*)d_in[4];
    const float* conv_b = (const float*)d_in[5];
    const float* dt_w   = (const float*)d_in[6];
    const float* dt_b   = (const float*)d_in[7];
    const float* A_log  = (const float*)d_in[8];
    const float* Dv     = (const float*)d_in[9];
    const float* Bp     = (const float*)d_in[10];
    const float* Cp     = (const float*)d_in[11];
    const float* Wout   = (const float*)d_in[12];
    float* out = (float*)d_out;

    char* w = (char*)d_ws;
    float* xz  = (float*)w;                   w += (size_t)NROWS * 4096 * 4;    // [2048][4096]
    float* xs  = (float*)w;                   w += (size_t)NROWS * D_INNER * 4; // post-conv silu f32
    float* xw2 = (float*)w;                   w += (size_t)NROWS * N2 * 4;      // dt_pre | Bt | Ct
    float* dt  = (float*)w;                   w += (size_t)NROWS * D_INNER * 4;
    float* yb  = (float*)w;                   w += (size_t)NROWS * D_INNER * 4;
    unsigned short* wt  = (unsigned short*)w; w += (size_t)N2 * D_INNER * 2;    // shared B^T buffer
    unsigned short* hb  = (unsigned short*)w; w += (size_t)NROWS * D_MODEL * 2;
    unsigned short* xsb = (unsigned short*)w; w += (size_t)NROWS * D_INNER * 2; // reused for y2b
    if ((size_t)(w - (char*)d_ws) > ws_size) return;

    // 1. LayerNorm -> bf16 h
    ln_k<<<NROWS, 256, 0, stream>>>(x, norm_w, norm_b, hb);
    // 2. Win^T -> bf16
    tcast<<<dim3(4096 / 32, 1024 / 32), 256, 0, stream>>>(Win, wt, 1024, 4096, 1024);
    // 3. xz = h @ Win
    gemm_bt<<<dim3(4096 / 128, 2048 / 128), 256, 0, stream>>>(hb, wt, xz, nullptr, 2048, 4096, 1024);
    // 4. causal conv + silu
    conv_silu<<<(NROWS * D_INNER) / 256, 256, 0, stream>>>(xz, conv_w, conv_b, xs, xsb);
    // 5. pack W2^T = [dt_w | Bp | Cp]^T -> bf16 [2176][2048]
    tcast<<<dim3(2048 / 32, 2048 / 32), 256, 0, stream>>>(dt_w, wt, 2048, 2048, 2048);
    tcast<<<dim3(64 / 32, 2048 / 32), 256, 0, stream>>>(Bp, wt + (size_t)2048 * 2048, 2048, 64, 2048);
    tcast<<<dim3(64 / 32, 2048 / 32), 256, 0, stream>>>(Cp, wt + (size_t)2112 * 2048, 2048, 64, 2048);
    // 6. xw2 = xs @ [dt_w | Bp | Cp]
    gemm_bt<<<dim3(2176 / 128, 2048 / 128), 256, 0, stream>>>(xsb, wt, xw2, nullptr, 2048, 2176, 2048);
    // 7. dt = softplus(dt_pre + dt_b)
    softplus_k<<<(NROWS * D_INNER) / 256, 256, 0, stream>>>(xw2, dt_b, dt);
    // 8. selective scan
    scan_k<<<4096 / 4, 256, 0, stream>>>(dt, xs, xw2, A_log, yb);
    // 9. combine -> bf16 y'
    combine_k<<<(NROWS * D_INNER) / 256, 256, 0, stream>>>(yb, xs, Dv, xz, xsb);
    // 10. Wout^T -> bf16
    tcast<<<dim3(1024 / 32, 2048 / 32), 256, 0, stream>>>(Wout, wt, 2048, 1024, 2048);
    // 11. out = x + y' @ Wout
    gemm_bt<<<dim3(1024 / 128, 2048 / 128), 256, 0, stream>>>(xsb, wt, out, x, 2048, 1024, 2048);
}